// Round 1
// baseline (4713.446 us; speedup 1.0000x reference)
//
#include <hip/hip_runtime.h>
#include <hip/hip_bf16.h>

namespace {

constexpr int Bc  = 2;
constexpr int Nc  = 16384;
constexpr int Rc  = 2048;
constexpr int CAc = 128;
constexpr int CSc = 256;
constexpr int CPc = 16;
constexpr int Hc  = 4;
constexpr int WQc = 32;
constexpr int WKc = 128;
constexpr int NWc = 512;
constexpr int CHc = 32;
constexpr float EPSf     = 1e-5f;
constexpr float NEG_INF  = -1e8f;
constexpr float QK_SCALE = 0.17677669529663687f;  // 1/sqrt(32)

__device__ __forceinline__ float wsum(float v) {
#pragma unroll
  for (int m = 1; m < 64; m <<= 1) v += __shfl_xor(v, m, 64);
  return v;
}
__device__ __forceinline__ float sigm(float x) { return 1.0f / (1.0f + __expf(-x)); }
__device__ __forceinline__ float f4c(const float4& v, int i) {
  return i == 0 ? v.x : i == 1 ? v.y : i == 2 ? v.z : v.w;
}

// ---------------- K1a: per-res LN (two weighted variants) ----------------
__global__ void k_res_ln(const float* __restrict__ res, const float* __restrict__ a_ln_w,
                         const float* __restrict__ t_ln_w, float* __restrict__ lnA,
                         float* __restrict__ lnT) {
  const int wid = threadIdx.x >> 6, lane = threadIdx.x & 63;
  const int row = blockIdx.x * 4 + wid;  // B*R rows
  const float* r = res + (size_t)row * CSc;
  float x[4], s = 0.f, sq = 0.f;
#pragma unroll
  for (int i = 0; i < 4; ++i) { x[i] = r[lane + 64 * i]; s += x[i]; sq += x[i] * x[i]; }
  s = wsum(s); sq = wsum(sq);
  const float mn = s * (1.0f / CSc);
  const float var = sq * (1.0f / CSc) - mn * mn;
  const float rs = rsqrtf(var + EPSf);
#pragma unroll
  for (int i = 0; i < 4; ++i) {
    const int c = lane + 64 * i;
    const float y = (x[i] - mn) * rs;
    lnA[(size_t)row * CSc + c] = y * a_ln_w[c];
    lnT[(size_t)row * CSc + c] = y * t_ln_w[c];
  }
}

// ---------------- K1b: 6 res GEMMs (K=256 -> 128 cols), gates sigmoid'd ----
__global__ void k_res_gemm(const float* __restrict__ lnA, const float* __restrict__ lnT,
                           const float* __restrict__ res,
                           const float* __restrict__ a_Wg, const float* __restrict__ a_bg,
                           const float* __restrict__ a_Wb,
                           const float* __restrict__ t_Wg, const float* __restrict__ t_bg,
                           const float* __restrict__ t_Wb,
                           const float* __restrict__ sg_W, const float* __restrict__ sg_b,
                           const float* __restrict__ t_Wc, const float* __restrict__ t_bc,
                           float* __restrict__ Ag, float* __restrict__ Ab,
                           float* __restrict__ Tg, float* __restrict__ Tb,
                           float* __restrict__ Sg, float* __restrict__ Tc) {
  __shared__ float tile[32 * CSc];
  const int m = blockIdx.y;
  const float* in = (m < 2) ? lnA : (m < 4) ? lnT : res;
  const float* W  = (m == 0) ? a_Wg : (m == 1) ? a_Wb : (m == 2) ? t_Wg
                  : (m == 3) ? t_Wb : (m == 4) ? sg_W : t_Wc;
  const float* bias = (m == 0) ? a_bg : (m == 2) ? t_bg : (m == 4) ? sg_b
                    : (m == 5) ? t_bc : nullptr;
  const bool sig = (m == 0) || (m == 2) || (m == 4) || (m == 5);
  float* out = (m == 0) ? Ag : (m == 1) ? Ab : (m == 2) ? Tg
             : (m == 3) ? Tb : (m == 4) ? Sg : Tc;
  const int row0 = blockIdx.x * 32;
  const float4* src = (const float4*)(in + (size_t)row0 * CSc);
  float4* dst = (float4*)tile;
#pragma unroll
  for (int k = 0; k < 8; ++k) dst[threadIdx.x + 256 * k] = src[threadIdx.x + 256 * k];
  __syncthreads();
  const int c0 = (threadIdx.x & 31) * 4;
  const int r0 = (threadIdx.x >> 5) * 4;
  float acc[4][4] = {};
  for (int j = 0; j < CSc; j += 4) {
    float4 a[4];
#pragma unroll
    for (int r = 0; r < 4; ++r) a[r] = *(const float4*)&tile[(r0 + r) * CSc + j];
#pragma unroll
    for (int jj = 0; jj < 4; ++jj) {
      const float4 w = *(const float4*)&W[(size_t)(j + jj) * CAc + c0];
#pragma unroll
      for (int r = 0; r < 4; ++r) {
        const float av = f4c(a[r], jj);
        acc[r][0] += av * w.x; acc[r][1] += av * w.y;
        acc[r][2] += av * w.z; acc[r][3] += av * w.w;
      }
    }
  }
  float4 bv = make_float4(0.f, 0.f, 0.f, 0.f);
  if (bias) bv = *(const float4*)&bias[c0];
#pragma unroll
  for (int r = 0; r < 4; ++r) {
    float4 o;
    o.x = acc[r][0] + bv.x; o.y = acc[r][1] + bv.y;
    o.z = acc[r][2] + bv.z; o.w = acc[r][3] + bv.w;
    if (sig) { o.x = sigm(o.x); o.y = sigm(o.y); o.z = sigm(o.z); o.w = sigm(o.w); }
    *(float4*)&out[(size_t)(row0 + r0 + r) * CAc + c0] = o;
  }
}

// ---------------- K2/K5: adaLN over atoms (row LN 128 + gather gate/bias) --
__global__ void k_adaln(const float* __restrict__ in, const int* __restrict__ idxG,
                        const float* __restrict__ G, const float* __restrict__ Bb,
                        float* __restrict__ out) {
  const int wid = threadIdx.x >> 6, lane = threadIdx.x & 63;
  const int row = blockIdx.x * 4 + wid;  // B*N rows
  const int b = row >> 14;
  const float* r = in + (size_t)row * CAc;
  const float x0 = r[lane], x1 = r[lane + 64];
  const float s = wsum(x0 + x1);
  const float sq = wsum(x0 * x0 + x1 * x1);
  const float mn = s * (1.0f / CAc);
  const float var = sq * (1.0f / CAc) - mn * mn;
  const float rs = rsqrtf(var + EPSf);
  const int base = (b * Rc + idxG[row]) * CAc;
  out[(size_t)row * CAc + lane]      = (x0 - mn) * rs * G[base + lane]      + Bb[base + lane];
  out[(size_t)row * CAc + lane + 64] = (x1 - mn) * rs * G[base + lane + 64] + Bb[base + lane + 64];
}

// ---------------- K3: q/kv projection GEMM (K=128) -------------------------
__global__ void k_qkv(const float* __restrict__ s, const float* __restrict__ q_W,
                      const float* __restrict__ q_b, const float* __restrict__ kv_W,
                      float* __restrict__ q, float* __restrict__ kv) {
  __shared__ float tile[32 * CAc];
  const int y = blockIdx.y;  // 0: q, 1: kv[0:128], 2: kv[128:256]
  const int row0 = blockIdx.x * 32;
  const float4* src = (const float4*)(s + (size_t)row0 * CAc);
  float4* dst = (float4*)tile;
#pragma unroll
  for (int k = 0; k < 4; ++k) dst[threadIdx.x + 256 * k] = src[threadIdx.x + 256 * k];
  __syncthreads();
  const int c0 = (threadIdx.x & 31) * 4;
  const int r0 = (threadIdx.x >> 5) * 4;
  const float* W = (y == 0) ? q_W : kv_W;
  const int wld = (y == 0) ? CAc : 2 * CAc;
  const int woff = (y == 2) ? CAc : 0;
  float acc[4][4] = {};
  for (int j = 0; j < CAc; j += 4) {
    float4 a[4];
#pragma unroll
    for (int r = 0; r < 4; ++r) a[r] = *(const float4*)&tile[(r0 + r) * CAc + j];
#pragma unroll
    for (int jj = 0; jj < 4; ++jj) {
      const float4 w = *(const float4*)&W[(size_t)(j + jj) * wld + woff + c0];
#pragma unroll
      for (int r = 0; r < 4; ++r) {
        const float av = f4c(a[r], jj);
        acc[r][0] += av * w.x; acc[r][1] += av * w.y;
        acc[r][2] += av * w.z; acc[r][3] += av * w.w;
      }
    }
  }
  float4 bv = make_float4(0.f, 0.f, 0.f, 0.f);
  if (y == 0) bv = *(const float4*)&q_b[c0];
#pragma unroll
  for (int r = 0; r < 4; ++r) {
    float4 o;
    o.x = acc[r][0] + bv.x; o.y = acc[r][1] + bv.y;
    o.z = acc[r][2] + bv.z; o.w = acc[r][3] + bv.w;
    const size_t row = (size_t)(row0 + r0 + r);
    if (y == 0) *(float4*)&q[row * CAc + c0] = o;
    else        *(float4*)&kv[row * 2 * CAc + woff + c0] = o;
  }
}

// ---------------- K4: fused windowed attention -----------------------------
__global__ __launch_bounds__(256) void k_attn(
    const float* __restrict__ qG, const float* __restrict__ kvG,
    const float* __restrict__ ap, const float* __restrict__ bw,
    const float* __restrict__ bb, const float* __restrict__ bW,
    const int* __restrict__ idxG, const float* __restrict__ SgG,
    const float* __restrict__ pmask, const float* __restrict__ atomF,
    float* __restrict__ atomO) {
  __shared__ __hip_bfloat16 sc[Hc][WQc][130];  // padded: stride 130*2B
  __shared__ float kvb[WKc][36];
  __shared__ float qb[WQc][36];
  __shared__ float bws[CPc], bbs[CPc], bWs[CPc * Hc];
  const int tid = threadIdx.x;
  const int bwid = blockIdx.x;
  const int b = bwid >> 9, w = bwid & 511;
  if (tid < CPc) { bws[tid] = bw[tid]; bbs[tid] = bb[tid]; }
  if (tid >= 64 && tid < 64 + CPc * Hc) bWs[tid - 64] = bW[tid - 64];
  __syncthreads();

  // Phase A: atompair LN -> bias for all heads, + window-validity mask
  const float* apw = ap + (size_t)bwid * WQc * WKc * CPc;
  for (int i = tid; i < WQc * WKc; i += 256) {
    const int qq = i >> 7, kk = i & 127;
    const float* p = apw + (size_t)i * CPc;
    float x[16];
    float s = 0.f;
#pragma unroll
    for (int t = 0; t < 4; ++t) {
      const float4 v4 = *(const float4*)&p[t * 4];
      x[4 * t] = v4.x; x[4 * t + 1] = v4.y; x[4 * t + 2] = v4.z; x[4 * t + 3] = v4.w;
      s += v4.x + v4.y + v4.z + v4.w;
    }
    const float mn = s * (1.0f / CPc);
    float vq = 0.f;
#pragma unroll
    for (int t = 0; t < 16; ++t) { const float d = x[t] - mn; vq += d * d; }
    const float rs = rsqrtf(vq * (1.0f / CPc) + EPSf);
    float bh[4] = {0.f, 0.f, 0.f, 0.f};
#pragma unroll
    for (int cp = 0; cp < 16; ++cp) {
      const float yv = (x[cp] - mn) * rs * bws[cp] + bbs[cp];
      bh[0] += yv * bWs[cp * 4 + 0]; bh[1] += yv * bWs[cp * 4 + 1];
      bh[2] += yv * bWs[cp * 4 + 2]; bh[3] += yv * bWs[cp * 4 + 3];
    }
    const int gk = w * 32 - 48 + kk;
    const float maskt = (gk >= 0 && gk < Nc) ? 0.f : NEG_INF;
#pragma unroll
    for (int h = 0; h < 4; ++h) sc[h][qq][kk] = __float2bfloat16(bh[h] + maskt);
  }
  __syncthreads();

  for (int h = 0; h < Hc; ++h) {
    // load q_h, k_h
    for (int i = tid; i < WQc * CHc; i += 256) {
      const int qq = i >> 5, d = i & 31;
      qb[qq][d] = qG[((size_t)b * Nc + w * 32 + qq) * CAc + h * 32 + d];
    }
    for (int i = tid; i < WKc * CHc; i += 256) {
      const int kk = i >> 5, d = i & 31;
      int gk = w * 32 - 48 + kk;
      gk = min(max(gk, 0), Nc - 1);
      kvb[kk][d] = kvG[((size_t)b * Nc + gk) * (2 * CAc) + h * 32 + d];
    }
    __syncthreads();
    // QK^T: qq per lane (broadcast kv reads), kg = tid>>5 covers 16 keys
    {
      const int qq = tid & 31, kg = tid >> 5;
      float4 qv[8];
#pragma unroll
      for (int j = 0; j < 8; ++j) qv[j] = *(const float4*)&qb[qq][j * 4];
#pragma unroll
      for (int k2 = 0; k2 < 16; ++k2) {
        const int kk = kg * 16 + k2;
        float acc = 0.f;
#pragma unroll
        for (int j = 0; j < 8; ++j) {
          const float4 kv4 = *(const float4*)&kvb[kk][j * 4];
          acc += qv[j].x * kv4.x + qv[j].y * kv4.y + qv[j].z * kv4.z + qv[j].w * kv4.w;
        }
        const float prev = __bfloat162float(sc[h][qq][kk]);
        sc[h][qq][kk] = __float2bfloat16(prev + acc * QK_SCALE);
      }
    }
    __syncthreads();
    // softmax over 128 keys, 8 threads per row
    {
      const int qq = tid >> 3, kg = tid & 7;
      float vals[16];
      float mx = -3e38f;
#pragma unroll
      for (int k2 = 0; k2 < 16; ++k2) {
        vals[k2] = __bfloat162float(sc[h][qq][kg * 16 + k2]);
        mx = fmaxf(mx, vals[k2]);
      }
#pragma unroll
      for (int mk = 1; mk <= 4; mk <<= 1) mx = fmaxf(mx, __shfl_xor(mx, mk, 64));
      float sm = 0.f;
#pragma unroll
      for (int k2 = 0; k2 < 16; ++k2) { vals[k2] = __expf(vals[k2] - mx); sm += vals[k2]; }
#pragma unroll
      for (int mk = 1; mk <= 4; mk <<= 1) sm += __shfl_xor(sm, mk, 64);
      const float inv = 1.0f / sm;
#pragma unroll
      for (int k2 = 0; k2 < 16; ++k2)
        sc[h][qq][kg * 16 + k2] = __float2bfloat16(vals[k2] * inv);
    }
    __syncthreads();
    // load v_h
    for (int i = tid; i < WKc * CHc; i += 256) {
      const int kk = i >> 5, d = i & 31;
      int gk = w * 32 - 48 + kk;
      gk = min(max(gk, 0), Nc - 1);
      kvb[kk][d] = kvG[((size_t)b * Nc + gk) * (2 * CAc) + CAc + h * 32 + d];
    }
    __syncthreads();
    // PV + gated residual epilogue
    {
      const int qq = tid >> 3, dg = tid & 7;
      float4 acc = make_float4(0.f, 0.f, 0.f, 0.f);
      for (int kk = 0; kk < WKc; ++kk) {
        const float p = __bfloat162float(sc[h][qq][kk]);
        const float4 v4 = *(const float4*)&kvb[kk][dg * 4];
        acc.x += p * v4.x; acc.y += p * v4.y; acc.z += p * v4.z; acc.w += p * v4.w;
      }
      const int n = w * 32 + qq;
      const int c = h * 32 + dg * 4;
      const int rowg = b * Nc + n;
      const int idx = idxG[rowg];
      const float4 g4 = *(const float4*)&SgG[(size_t)(b * Rc + idx) * CAc + c];
      const float pm = pmask[rowg];
      const float4 af = *(const float4*)&atomF[(size_t)rowg * CAc + c];
      float4 o;
      o.x = af.x + acc.x * g4.x * pm; o.y = af.y + acc.y * g4.y * pm;
      o.z = af.z + acc.z * g4.z * pm; o.w = af.w + acc.w * g4.w * pm;
      *(float4*)&atomO[(size_t)rowg * CAc + c] = o;
    }
    __syncthreads();
  }
}

// ---------------- K6: transition part 1 (silu(t@W1)*(t@W2)) ---------------
__global__ void k_trans1(const float* __restrict__ t, const float* __restrict__ W1,
                         const float* __restrict__ W2, float* __restrict__ bmid) {
  __shared__ float tile[32 * CAc];
  const int row0 = blockIdx.x * 32;
  const int ct = blockIdx.y;  // col half of 256
  const float4* src = (const float4*)(t + (size_t)row0 * CAc);
  float4* dst = (float4*)tile;
#pragma unroll
  for (int k = 0; k < 4; ++k) dst[threadIdx.x + 256 * k] = src[threadIdx.x + 256 * k];
  __syncthreads();
  const int c0 = (threadIdx.x & 31) * 4;
  const int r0 = (threadIdx.x >> 5) * 4;
  const int cc = ct * 128 + c0;
  float acc1[4][4] = {}, acc2[4][4] = {};
  for (int j = 0; j < CAc; j += 4) {
    float4 a[4];
#pragma unroll
    for (int r = 0; r < 4; ++r) a[r] = *(const float4*)&tile[(r0 + r) * CAc + j];
#pragma unroll
    for (int jj = 0; jj < 4; ++jj) {
      const float4 w1 = *(const float4*)&W1[(size_t)(j + jj) * 256 + cc];
      const float4 w2 = *(const float4*)&W2[(size_t)(j + jj) * 256 + cc];
#pragma unroll
      for (int r = 0; r < 4; ++r) {
        const float av = f4c(a[r], jj);
        acc1[r][0] += av * w1.x; acc1[r][1] += av * w1.y;
        acc1[r][2] += av * w1.z; acc1[r][3] += av * w1.w;
        acc2[r][0] += av * w2.x; acc2[r][1] += av * w2.y;
        acc2[r][2] += av * w2.z; acc2[r][3] += av * w2.w;
      }
    }
  }
#pragma unroll
  for (int r = 0; r < 4; ++r) {
    float4 o;
    o.x = acc1[r][0] * sigm(acc1[r][0]) * acc2[r][0];
    o.y = acc1[r][1] * sigm(acc1[r][1]) * acc2[r][1];
    o.z = acc1[r][2] * sigm(acc1[r][2]) * acc2[r][2];
    o.w = acc1[r][3] * sigm(acc1[r][3]) * acc2[r][3];
    *(float4*)&bmid[(size_t)(row0 + r0 + r) * 256 + cc] = o;
  }
}

// ---------------- K7: transition part 2 + final residual -------------------
__global__ void k_trans2(const float* __restrict__ bm, const float* __restrict__ Wo,
                         const float* __restrict__ atomw, const int* __restrict__ idxG,
                         const float* __restrict__ TcG, const float* __restrict__ pmask,
                         float* __restrict__ outG) {
  __shared__ float tile[32 * 256];
  const int row0 = blockIdx.x * 32;
  const float4* src = (const float4*)(bm + (size_t)row0 * 256);
  float4* dst = (float4*)tile;
#pragma unroll
  for (int k = 0; k < 8; ++k) dst[threadIdx.x + 256 * k] = src[threadIdx.x + 256 * k];
  __syncthreads();
  const int c0 = (threadIdx.x & 31) * 4;
  const int r0 = (threadIdx.x >> 5) * 4;
  float acc[4][4] = {};
  for (int j = 0; j < 256; j += 4) {
    float4 a[4];
#pragma unroll
    for (int r = 0; r < 4; ++r) a[r] = *(const float4*)&tile[(r0 + r) * 256 + j];
#pragma unroll
    for (int jj = 0; jj < 4; ++jj) {
      const float4 w = *(const float4*)&Wo[(size_t)(j + jj) * CAc + c0];
#pragma unroll
      for (int r = 0; r < 4; ++r) {
        const float av = f4c(a[r], jj);
        acc[r][0] += av * w.x; acc[r][1] += av * w.y;
        acc[r][2] += av * w.z; acc[r][3] += av * w.w;
      }
    }
  }
#pragma unroll
  for (int r = 0; r < 4; ++r) {
    const int row = row0 + r0 + r;
    const int b = row >> 14;
    const int idx = idxG[row];
    const float pm = pmask[row];
    const float4 tc = *(const float4*)&TcG[(size_t)(b * Rc + idx) * CAc + c0];
    const float4 at = *(const float4*)&atomw[(size_t)row * CAc + c0];
    float4 o;
    o.x = at.x + tc.x * acc[r][0] * pm; o.y = at.y + tc.y * acc[r][1] * pm;
    o.z = at.z + tc.z * acc[r][2] * pm; o.w = at.w + tc.w * acc[r][3] * pm;
    *(float4*)&outG[(size_t)row * CAc + c0] = o;
  }
}

}  // namespace

extern "C" void kernel_launch(void* const* d_in, const int* in_sizes, int n_in,
                              void* d_out, int out_size, void* d_ws, size_t ws_size,
                              hipStream_t stream) {
  (void)in_sizes; (void)n_in; (void)out_size; (void)ws_size;
  const float* atomF   = (const float*)d_in[0];
  const float* resF    = (const float*)d_in[1];
  const float* apF     = (const float*)d_in[2];
  const int*   idx     = (const int*)d_in[3];
  const float* pmask   = (const float*)d_in[4];
  // d_in[5] atompair_mask: validity recomputed in-kernel
  const float* a_ln_w  = (const float*)d_in[6];
  const float* a_Wg    = (const float*)d_in[7];
  const float* a_bg    = (const float*)d_in[8];
  const float* a_Wb    = (const float*)d_in[9];
  const float* q_W     = (const float*)d_in[10];
  const float* q_b     = (const float*)d_in[11];
  const float* kv_W    = (const float*)d_in[12];
  const float* bij_ln_w= (const float*)d_in[13];
  const float* bij_ln_b= (const float*)d_in[14];
  const float* bij_W   = (const float*)d_in[15];
  const float* sg_W    = (const float*)d_in[16];
  const float* sg_b    = (const float*)d_in[17];
  const float* t_ln_w  = (const float*)d_in[18];
  const float* t_Wg    = (const float*)d_in[19];
  const float* t_bg    = (const float*)d_in[20];
  const float* t_Wb    = (const float*)d_in[21];
  const float* t_W1    = (const float*)d_in[22];
  const float* t_W2    = (const float*)d_in[23];
  const float* t_Wc    = (const float*)d_in[24];
  const float* t_bc    = (const float*)d_in[25];
  const float* t_Wo    = (const float*)d_in[26];

  float* ws    = (float*)d_ws;
  float* Ag    = ws;                      // B*R*CA = 524288 each
  float* Ab    = Ag + 524288;
  float* Tg    = Ab + 524288;
  float* Tb    = Tg + 524288;
  float* Sg    = Tb + 524288;
  float* Tc    = Sg + 524288;
  float* lnA   = Tc + 524288;             // B*R*CS = 1048576 each
  float* lnT   = lnA + 1048576;
  float* sbuf  = lnT + 1048576;           // B*N*CA = 4194304  (s, later t)
  float* qbuf  = sbuf + 4194304;          // B*N*CA
  float* kvbuf = qbuf + 4194304;          // B*N*2CA = 8388608
  float* atomw = kvbuf + 8388608;         // B*N*CA
  float* bmid  = qbuf;                    // reuse q+kv region after attention

  k_res_ln<<<dim3(Bc * Rc / 4), dim3(256), 0, stream>>>(resF, a_ln_w, t_ln_w, lnA, lnT);
  k_res_gemm<<<dim3(Bc * Rc / 32, 6), dim3(256), 0, stream>>>(
      lnA, lnT, resF, a_Wg, a_bg, a_Wb, t_Wg, t_bg, t_Wb, sg_W, sg_b, t_Wc, t_bc,
      Ag, Ab, Tg, Tb, Sg, Tc);
  k_adaln<<<dim3(Bc * Nc / 4), dim3(256), 0, stream>>>(atomF, idx, Ag, Ab, sbuf);
  k_qkv<<<dim3(Bc * Nc / 32, 3), dim3(256), 0, stream>>>(sbuf, q_W, q_b, kv_W, qbuf, kvbuf);
  k_attn<<<dim3(Bc * NWc), dim3(256), 0, stream>>>(qbuf, kvbuf, apF, bij_ln_w, bij_ln_b,
                                                   bij_W, idx, Sg, pmask, atomF, atomw);
  k_adaln<<<dim3(Bc * Nc / 4), dim3(256), 0, stream>>>(atomw, idx, Tg, Tb, sbuf);
  k_trans1<<<dim3(Bc * Nc / 32, 2), dim3(256), 0, stream>>>(sbuf, t_W1, t_W2, bmid);
  k_trans2<<<dim3(Bc * Nc / 32), dim3(256), 0, stream>>>(bmid, t_Wo, atomw, idx, Tc, pmask,
                                                         (float*)d_out);
}

// Round 2
// 455.228 us; speedup vs baseline: 10.3540x; 10.3540x over previous
//
#include <hip/hip_runtime.h>
#include <hip/hip_bf16.h>

namespace {

constexpr int Bc  = 2;
constexpr int Nc  = 16384;
constexpr int Rc  = 2048;
constexpr int CAc = 128;
constexpr int CSc = 256;
constexpr int CPc = 16;
constexpr int Hc  = 4;
constexpr int WQc = 32;
constexpr int WKc = 128;
constexpr int NWc = 512;
constexpr int CHc = 32;
constexpr float EPSf     = 1e-5f;
constexpr float NEG_INF  = -1e8f;
constexpr float QK_SCALE = 0.17677669529663687f;  // 1/sqrt(32)

__device__ __forceinline__ float wsum(float v) {
#pragma unroll
  for (int m = 1; m < 64; m <<= 1) v += __shfl_xor(v, m, 64);
  return v;
}
__device__ __forceinline__ float sigm(float x) { return 1.0f / (1.0f + __expf(-x)); }
__device__ __forceinline__ float f4c(const float4& v, int i) {
  return i == 0 ? v.x : i == 1 ? v.y : i == 2 ? v.z : v.w;
}

// ---------------- K1a: per-res LN (two weighted variants) ----------------
__global__ void k_res_ln(const float* __restrict__ res, const float* __restrict__ a_ln_w,
                         const float* __restrict__ t_ln_w, float* __restrict__ lnA,
                         float* __restrict__ lnT) {
  const int wid = threadIdx.x >> 6, lane = threadIdx.x & 63;
  const int row = blockIdx.x * 4 + wid;  // B*R rows
  const float* r = res + (size_t)row * CSc;
  float x[4], s = 0.f, sq = 0.f;
#pragma unroll
  for (int i = 0; i < 4; ++i) { x[i] = r[lane + 64 * i]; s += x[i]; sq += x[i] * x[i]; }
  s = wsum(s); sq = wsum(sq);
  const float mn = s * (1.0f / CSc);
  const float var = sq * (1.0f / CSc) - mn * mn;
  const float rs = rsqrtf(var + EPSf);
#pragma unroll
  for (int i = 0; i < 4; ++i) {
    const int c = lane + 64 * i;
    const float y = (x[i] - mn) * rs;
    lnA[(size_t)row * CSc + c] = y * a_ln_w[c];
    lnT[(size_t)row * CSc + c] = y * t_ln_w[c];
  }
}

// ---------------- K1b: 6 res GEMMs (K=256 -> 128 cols), gates sigmoid'd ----
__global__ void k_res_gemm(const float* __restrict__ lnA, const float* __restrict__ lnT,
                           const float* __restrict__ res,
                           const float* __restrict__ a_Wg, const float* __restrict__ a_bg,
                           const float* __restrict__ a_Wb,
                           const float* __restrict__ t_Wg, const float* __restrict__ t_bg,
                           const float* __restrict__ t_Wb,
                           const float* __restrict__ sg_W, const float* __restrict__ sg_b,
                           const float* __restrict__ t_Wc, const float* __restrict__ t_bc,
                           float* __restrict__ Ag, float* __restrict__ Ab,
                           float* __restrict__ Tg, float* __restrict__ Tb,
                           float* __restrict__ Sg, float* __restrict__ Tc) {
  __shared__ float tile[32 * CSc];
  const int m = blockIdx.y;
  const float* in = (m < 2) ? lnA : (m < 4) ? lnT : res;
  const float* W  = (m == 0) ? a_Wg : (m == 1) ? a_Wb : (m == 2) ? t_Wg
                  : (m == 3) ? t_Wb : (m == 4) ? sg_W : t_Wc;
  const float* bias = (m == 0) ? a_bg : (m == 2) ? t_bg : (m == 4) ? sg_b
                    : (m == 5) ? t_bc : nullptr;
  const bool sig = (m == 0) || (m == 2) || (m == 4) || (m == 5);
  float* out = (m == 0) ? Ag : (m == 1) ? Ab : (m == 2) ? Tg
             : (m == 3) ? Tb : (m == 4) ? Sg : Tc;
  const int row0 = blockIdx.x * 32;
  const float4* src = (const float4*)(in + (size_t)row0 * CSc);
  float4* dst = (float4*)tile;
#pragma unroll
  for (int k = 0; k < 8; ++k) dst[threadIdx.x + 256 * k] = src[threadIdx.x + 256 * k];
  __syncthreads();
  const int c0 = (threadIdx.x & 31) * 4;
  const int r0 = (threadIdx.x >> 5) * 4;
  float acc[4][4] = {};
  for (int j = 0; j < CSc; j += 4) {
    float4 a[4];
#pragma unroll
    for (int r = 0; r < 4; ++r) a[r] = *(const float4*)&tile[(r0 + r) * CSc + j];
#pragma unroll
    for (int jj = 0; jj < 4; ++jj) {
      const float4 w = *(const float4*)&W[(size_t)(j + jj) * CAc + c0];
#pragma unroll
      for (int r = 0; r < 4; ++r) {
        const float av = f4c(a[r], jj);
        acc[r][0] += av * w.x; acc[r][1] += av * w.y;
        acc[r][2] += av * w.z; acc[r][3] += av * w.w;
      }
    }
  }
  float4 bv = make_float4(0.f, 0.f, 0.f, 0.f);
  if (bias) bv = *(const float4*)&bias[c0];
#pragma unroll
  for (int r = 0; r < 4; ++r) {
    float4 o;
    o.x = acc[r][0] + bv.x; o.y = acc[r][1] + bv.y;
    o.z = acc[r][2] + bv.z; o.w = acc[r][3] + bv.w;
    if (sig) { o.x = sigm(o.x); o.y = sigm(o.y); o.z = sigm(o.z); o.w = sigm(o.w); }
    *(float4*)&out[(size_t)(row0 + r0 + r) * CAc + c0] = o;
  }
}

// ---------------- K2/K5: adaLN over atoms (row LN 128 + gather gate/bias) --
__global__ void k_adaln(const float* __restrict__ in, const int* __restrict__ idxG,
                        const float* __restrict__ G, const float* __restrict__ Bb,
                        float* __restrict__ out) {
  const int wid = threadIdx.x >> 6, lane = threadIdx.x & 63;
  const int row = blockIdx.x * 4 + wid;  // B*N rows
  const int b = row >> 14;
  const float* r = in + (size_t)row * CAc;
  const float x0 = r[lane], x1 = r[lane + 64];
  const float s = wsum(x0 + x1);
  const float sq = wsum(x0 * x0 + x1 * x1);
  const float mn = s * (1.0f / CAc);
  const float var = sq * (1.0f / CAc) - mn * mn;
  const float rs = rsqrtf(var + EPSf);
  const int base = (b * Rc + idxG[row]) * CAc;
  out[(size_t)row * CAc + lane]      = (x0 - mn) * rs * G[base + lane]      + Bb[base + lane];
  out[(size_t)row * CAc + lane + 64] = (x1 - mn) * rs * G[base + lane + 64] + Bb[base + lane + 64];
}

// ---------------- K3: q/kv projection GEMM, W staged in LDS ----------------
// 64 rows/block, all 384 output cols (q:128, kv:256) per block.
// No per-lane global W loads: W chunks (32 K-rows x 128 cols) staged in LDS.
__global__ __launch_bounds__(256) void k_qkv2(
    const float* __restrict__ s, const float* __restrict__ q_W,
    const float* __restrict__ q_b, const float* __restrict__ kv_W,
    float* __restrict__ q, float* __restrict__ kv) {
  __shared__ float stile[64 * CAc];   // 32 KB
  __shared__ float wbuf[32 * 132];    // 16.5 KB (pad 132 floats/row)
  const int tid = threadIdx.x;
  const int row0 = blockIdx.x * 64;
  {
    const float4* src = (const float4*)(s + (size_t)row0 * CAc);
    float4* dst = (float4*)stile;
#pragma unroll
    for (int k = 0; k < 8; ++k) dst[tid + 256 * k] = src[tid + 256 * k];
  }
  const int c0 = (tid & 31) * 4;
  const int r0 = (tid >> 5) * 8;
#pragma unroll
  for (int cg = 0; cg < 3; ++cg) {
    const float* W  = (cg == 0) ? q_W : kv_W;
    const int wld   = (cg == 0) ? CAc : 2 * CAc;
    const int woff  = (cg == 2) ? CAc : 0;
    float acc[8][4] = {};
    for (int kc = 0; kc < 4; ++kc) {
      __syncthreads();  // protect wbuf from previous chunk's readers (and cover stile 1st time)
#pragma unroll
      for (int u = 0; u < 4; ++u) {
        const int i = tid + 256 * u;          // 1024 float4 = 32x128 floats
        const int rr = i >> 5, cc = i & 31;
        *(float4*)&wbuf[rr * 132 + cc * 4] =
            *(const float4*)&W[(size_t)(kc * 32 + rr) * wld + woff + cc * 4];
      }
      __syncthreads();
      for (int j4 = 0; j4 < 8; ++j4) {
        float4 a[8];
#pragma unroll
        for (int r = 0; r < 8; ++r)
          a[r] = *(const float4*)&stile[(r0 + r) * CAc + kc * 32 + j4 * 4];
#pragma unroll
        for (int jj = 0; jj < 4; ++jj) {
          const float4 w = *(const float4*)&wbuf[(j4 * 4 + jj) * 132 + c0];
#pragma unroll
          for (int r = 0; r < 8; ++r) {
            const float av = f4c(a[r], jj);
            acc[r][0] += av * w.x; acc[r][1] += av * w.y;
            acc[r][2] += av * w.z; acc[r][3] += av * w.w;
          }
        }
      }
    }
    float4 bv = make_float4(0.f, 0.f, 0.f, 0.f);
    if (cg == 0) bv = *(const float4*)&q_b[c0];
#pragma unroll
    for (int r = 0; r < 8; ++r) {
      float4 o;
      o.x = acc[r][0] + bv.x; o.y = acc[r][1] + bv.y;
      o.z = acc[r][2] + bv.z; o.w = acc[r][3] + bv.w;
      const size_t row = (size_t)(row0 + r0 + r);
      if (cg == 0) *(float4*)&q[row * CAc + c0] = o;
      else         *(float4*)&kv[row * 2 * CAc + woff + c0] = o;
    }
  }
}

// ---------------- K4: fused windowed attention -----------------------------
__global__ __launch_bounds__(256) void k_attn(
    const float* __restrict__ qG, const float* __restrict__ kvG,
    const float* __restrict__ ap, const float* __restrict__ bw,
    const float* __restrict__ bb, const float* __restrict__ bW,
    const int* __restrict__ idxG, const float* __restrict__ SgG,
    const float* __restrict__ pmask, const float* __restrict__ atomF,
    float* __restrict__ atomO) {
  __shared__ __hip_bfloat16 sc[Hc][WQc][130];  // padded: stride 130*2B
  __shared__ float kvb[WKc][36];
  __shared__ float qb[WQc][36];
  __shared__ float bws[CPc], bbs[CPc], bWs[CPc * Hc];
  const int tid = threadIdx.x;
  const int bwid = blockIdx.x;
  const int b = bwid >> 9, w = bwid & 511;
  if (tid < CPc) { bws[tid] = bw[tid]; bbs[tid] = bb[tid]; }
  if (tid >= 64 && tid < 64 + CPc * Hc) bWs[tid - 64] = bW[tid - 64];
  __syncthreads();

  // Phase A: atompair LN -> bias for all heads, + window-validity mask
  const float* apw = ap + (size_t)bwid * WQc * WKc * CPc;
  for (int i = tid; i < WQc * WKc; i += 256) {
    const int qq = i >> 7, kk = i & 127;
    const float* p = apw + (size_t)i * CPc;
    float x[16];
    float s = 0.f;
#pragma unroll
    for (int t = 0; t < 4; ++t) {
      const float4 v4 = *(const float4*)&p[t * 4];
      x[4 * t] = v4.x; x[4 * t + 1] = v4.y; x[4 * t + 2] = v4.z; x[4 * t + 3] = v4.w;
      s += v4.x + v4.y + v4.z + v4.w;
    }
    const float mn = s * (1.0f / CPc);
    float vq = 0.f;
#pragma unroll
    for (int t = 0; t < 16; ++t) { const float d = x[t] - mn; vq += d * d; }
    const float rs = rsqrtf(vq * (1.0f / CPc) + EPSf);
    float bh[4] = {0.f, 0.f, 0.f, 0.f};
#pragma unroll
    for (int cp = 0; cp < 16; ++cp) {
      const float yv = (x[cp] - mn) * rs * bws[cp] + bbs[cp];
      bh[0] += yv * bWs[cp * 4 + 0]; bh[1] += yv * bWs[cp * 4 + 1];
      bh[2] += yv * bWs[cp * 4 + 2]; bh[3] += yv * bWs[cp * 4 + 3];
    }
    const int gk = w * 32 - 48 + kk;
    const float maskt = (gk >= 0 && gk < Nc) ? 0.f : NEG_INF;
#pragma unroll
    for (int h = 0; h < 4; ++h) sc[h][qq][kk] = __float2bfloat16(bh[h] + maskt);
  }
  __syncthreads();

  for (int h = 0; h < Hc; ++h) {
    // load q_h, k_h
    for (int i = tid; i < WQc * CHc; i += 256) {
      const int qq = i >> 5, d = i & 31;
      qb[qq][d] = qG[((size_t)b * Nc + w * 32 + qq) * CAc + h * 32 + d];
    }
    for (int i = tid; i < WKc * CHc; i += 256) {
      const int kk = i >> 5, d = i & 31;
      int gk = w * 32 - 48 + kk;
      gk = min(max(gk, 0), Nc - 1);
      kvb[kk][d] = kvG[((size_t)b * Nc + gk) * (2 * CAc) + h * 32 + d];
    }
    __syncthreads();
    // QK^T: qq per lane (broadcast kv reads), kg = tid>>5 covers 16 keys
    {
      const int qq = tid & 31, kg = tid >> 5;
      float4 qv[8];
#pragma unroll
      for (int j = 0; j < 8; ++j) qv[j] = *(const float4*)&qb[qq][j * 4];
#pragma unroll
      for (int k2 = 0; k2 < 16; ++k2) {
        const int kk = kg * 16 + k2;
        float acc = 0.f;
#pragma unroll
        for (int j = 0; j < 8; ++j) {
          const float4 kv4 = *(const float4*)&kvb[kk][j * 4];
          acc += qv[j].x * kv4.x + qv[j].y * kv4.y + qv[j].z * kv4.z + qv[j].w * kv4.w;
        }
        const float prev = __bfloat162float(sc[h][qq][kk]);
        sc[h][qq][kk] = __float2bfloat16(prev + acc * QK_SCALE);
      }
    }
    __syncthreads();
    // softmax over 128 keys, 8 threads per row
    {
      const int qq = tid >> 3, kg = tid & 7;
      float vals[16];
      float mx = -3e38f;
#pragma unroll
      for (int k2 = 0; k2 < 16; ++k2) {
        vals[k2] = __bfloat162float(sc[h][qq][kg * 16 + k2]);
        mx = fmaxf(mx, vals[k2]);
      }
#pragma unroll
      for (int mk = 1; mk <= 4; mk <<= 1) mx = fmaxf(mx, __shfl_xor(mx, mk, 64));
      float sm = 0.f;
#pragma unroll
      for (int k2 = 0; k2 < 16; ++k2) { vals[k2] = __expf(vals[k2] - mx); sm += vals[k2]; }
#pragma unroll
      for (int mk = 1; mk <= 4; mk <<= 1) sm += __shfl_xor(sm, mk, 64);
      const float inv = 1.0f / sm;
#pragma unroll
      for (int k2 = 0; k2 < 16; ++k2)
        sc[h][qq][kg * 16 + k2] = __float2bfloat16(vals[k2] * inv);
    }
    __syncthreads();
    // load v_h
    for (int i = tid; i < WKc * CHc; i += 256) {
      const int kk = i >> 5, d = i & 31;
      int gk = w * 32 - 48 + kk;
      gk = min(max(gk, 0), Nc - 1);
      kvb[kk][d] = kvG[((size_t)b * Nc + gk) * (2 * CAc) + CAc + h * 32 + d];
    }
    __syncthreads();
    // PV + gated residual epilogue
    {
      const int qq = tid >> 3, dg = tid & 7;
      float4 acc = make_float4(0.f, 0.f, 0.f, 0.f);
      for (int kk = 0; kk < WKc; ++kk) {
        const float p = __bfloat162float(sc[h][qq][kk]);
        const float4 v4 = *(const float4*)&kvb[kk][dg * 4];
        acc.x += p * v4.x; acc.y += p * v4.y; acc.z += p * v4.z; acc.w += p * v4.w;
      }
      const int n = w * 32 + qq;
      const int c = h * 32 + dg * 4;
      const int rowg = b * Nc + n;
      const int idx = idxG[rowg];
      const float4 g4 = *(const float4*)&SgG[(size_t)(b * Rc + idx) * CAc + c];
      const float pm = pmask[rowg];
      const float4 af = *(const float4*)&atomF[(size_t)rowg * CAc + c];
      float4 o;
      o.x = af.x + acc.x * g4.x * pm; o.y = af.y + acc.y * g4.y * pm;
      o.z = af.z + acc.z * g4.z * pm; o.w = af.w + acc.w * g4.w * pm;
      *(float4*)&atomO[(size_t)rowg * CAc + c] = o;
    }
    __syncthreads();
  }
}

// ---------------- K6: transition part 1 (silu(t@W1)*(t@W2)) ---------------
__global__ void k_trans1(const float* __restrict__ t, const float* __restrict__ W1,
                         const float* __restrict__ W2, float* __restrict__ bmid) {
  __shared__ float tile[32 * CAc];
  const int row0 = blockIdx.x * 32;
  const int ct = blockIdx.y;  // col half of 256
  const float4* src = (const float4*)(t + (size_t)row0 * CAc);
  float4* dst = (float4*)tile;
#pragma unroll
  for (int k = 0; k < 4; ++k) dst[threadIdx.x + 256 * k] = src[threadIdx.x + 256 * k];
  __syncthreads();
  const int c0 = (threadIdx.x & 31) * 4;
  const int r0 = (threadIdx.x >> 5) * 4;
  const int cc = ct * 128 + c0;
  float acc1[4][4] = {}, acc2[4][4] = {};
  for (int j = 0; j < CAc; j += 4) {
    float4 a[4];
#pragma unroll
    for (int r = 0; r < 4; ++r) a[r] = *(const float4*)&tile[(r0 + r) * CAc + j];
#pragma unroll
    for (int jj = 0; jj < 4; ++jj) {
      const float4 w1 = *(const float4*)&W1[(size_t)(j + jj) * 256 + cc];
      const float4 w2 = *(const float4*)&W2[(size_t)(j + jj) * 256 + cc];
#pragma unroll
      for (int r = 0; r < 4; ++r) {
        const float av = f4c(a[r], jj);
        acc1[r][0] += av * w1.x; acc1[r][1] += av * w1.y;
        acc1[r][2] += av * w1.z; acc1[r][3] += av * w1.w;
        acc2[r][0] += av * w2.x; acc2[r][1] += av * w2.y;
        acc2[r][2] += av * w2.z; acc2[r][3] += av * w2.w;
      }
    }
  }
#pragma unroll
  for (int r = 0; r < 4; ++r) {
    float4 o;
    o.x = acc1[r][0] * sigm(acc1[r][0]) * acc2[r][0];
    o.y = acc1[r][1] * sigm(acc1[r][1]) * acc2[r][1];
    o.z = acc1[r][2] * sigm(acc1[r][2]) * acc2[r][2];
    o.w = acc1[r][3] * sigm(acc1[r][3]) * acc2[r][3];
    *(float4*)&bmid[(size_t)(row0 + r0 + r) * 256 + cc] = o;
  }
}

// ---------------- K7: transition part 2 + final residual -------------------
__global__ void k_trans2(const float* __restrict__ bm, const float* __restrict__ Wo,
                         const float* __restrict__ atomw, const int* __restrict__ idxG,
                         const float* __restrict__ TcG, const float* __restrict__ pmask,
                         float* __restrict__ outG) {
  __shared__ float tile[32 * 256];
  const int row0 = blockIdx.x * 32;
  const float4* src = (const float4*)(bm + (size_t)row0 * 256);
  float4* dst = (float4*)tile;
#pragma unroll
  for (int k = 0; k < 8; ++k) dst[threadIdx.x + 256 * k] = src[threadIdx.x + 256 * k];
  __syncthreads();
  const int c0 = (threadIdx.x & 31) * 4;
  const int r0 = (threadIdx.x >> 5) * 4;
  float acc[4][4] = {};
  for (int j = 0; j < 256; j += 4) {
    float4 a[4];
#pragma unroll
    for (int r = 0; r < 4; ++r) a[r] = *(const float4*)&tile[(r0 + r) * 256 + j];
#pragma unroll
    for (int jj = 0; jj < 4; ++jj) {
      const float4 w = *(const float4*)&Wo[(size_t)(j + jj) * CAc + c0];
#pragma unroll
      for (int r = 0; r < 4; ++r) {
        const float av = f4c(a[r], jj);
        acc[r][0] += av * w.x; acc[r][1] += av * w.y;
        acc[r][2] += av * w.z; acc[r][3] += av * w.w;
      }
    }
  }
#pragma unroll
  for (int r = 0; r < 4; ++r) {
    const int row = row0 + r0 + r;
    const int b = row >> 14;
    const int idx = idxG[row];
    const float pm = pmask[row];
    const float4 tc = *(const float4*)&TcG[(size_t)(b * Rc + idx) * CAc + c0];
    const float4 at = *(const float4*)&atomw[(size_t)row * CAc + c0];
    float4 o;
    o.x = at.x + tc.x * acc[r][0] * pm; o.y = at.y + tc.y * acc[r][1] * pm;
    o.z = at.z + tc.z * acc[r][2] * pm; o.w = at.w + tc.w * acc[r][3] * pm;
    *(float4*)&outG[(size_t)row * CAc + c0] = o;
  }
}

}  // namespace

extern "C" void kernel_launch(void* const* d_in, const int* in_sizes, int n_in,
                              void* d_out, int out_size, void* d_ws, size_t ws_size,
                              hipStream_t stream) {
  (void)in_sizes; (void)n_in; (void)out_size; (void)ws_size;
  const float* atomF   = (const float*)d_in[0];
  const float* resF    = (const float*)d_in[1];
  const float* apF     = (const float*)d_in[2];
  const int*   idx     = (const int*)d_in[3];
  const float* pmask   = (const float*)d_in[4];
  // d_in[5] atompair_mask: validity recomputed in-kernel
  const float* a_ln_w  = (const float*)d_in[6];
  const float* a_Wg    = (const float*)d_in[7];
  const float* a_bg    = (const float*)d_in[8];
  const float* a_Wb    = (const float*)d_in[9];
  const float* q_W     = (const float*)d_in[10];
  const float* q_b     = (const float*)d_in[11];
  const float* kv_W    = (const float*)d_in[12];
  const float* bij_ln_w= (const float*)d_in[13];
  const float* bij_ln_b= (const float*)d_in[14];
  const float* bij_W   = (const float*)d_in[15];
  const float* sg_W    = (const float*)d_in[16];
  const float* sg_b    = (const float*)d_in[17];
  const float* t_ln_w  = (const float*)d_in[18];
  const float* t_Wg    = (const float*)d_in[19];
  const float* t_bg    = (const float*)d_in[20];
  const float* t_Wb    = (const float*)d_in[21];
  const float* t_W1    = (const float*)d_in[22];
  const float* t_W2    = (const float*)d_in[23];
  const float* t_Wc    = (const float*)d_in[24];
  const float* t_bc    = (const float*)d_in[25];
  const float* t_Wo    = (const float*)d_in[26];

  float* ws    = (float*)d_ws;
  float* Ag    = ws;                      // B*R*CA = 524288 each
  float* Ab    = Ag + 524288;
  float* Tg    = Ab + 524288;
  float* Tb    = Tg + 524288;
  float* Sg    = Tb + 524288;
  float* Tc    = Sg + 524288;
  float* lnA   = Tc + 524288;             // B*R*CS = 1048576 each
  float* lnT   = lnA + 1048576;
  float* sbuf  = lnT + 1048576;           // B*N*CA = 4194304  (s, later t)
  float* qbuf  = sbuf + 4194304;          // B*N*CA
  float* kvbuf = qbuf + 4194304;          // B*N*2CA = 8388608
  float* atomw = kvbuf + 8388608;         // B*N*CA
  float* bmid  = qbuf;                    // reuse q+kv region after attention

  k_res_ln<<<dim3(Bc * Rc / 4), dim3(256), 0, stream>>>(resF, a_ln_w, t_ln_w, lnA, lnT);
  k_res_gemm<<<dim3(Bc * Rc / 32, 6), dim3(256), 0, stream>>>(
      lnA, lnT, resF, a_Wg, a_bg, a_Wb, t_Wg, t_bg, t_Wb, sg_W, sg_b, t_Wc, t_bc,
      Ag, Ab, Tg, Tb, Sg, Tc);
  k_adaln<<<dim3(Bc * Nc / 4), dim3(256), 0, stream>>>(atomF, idx, Ag, Ab, sbuf);
  k_qkv2<<<dim3(Bc * Nc / 64), dim3(256), 0, stream>>>(sbuf, q_W, q_b, kv_W, qbuf, kvbuf);
  k_attn<<<dim3(Bc * NWc), dim3(256), 0, stream>>>(qbuf, kvbuf, apF, bij_ln_w, bij_ln_b,
                                                   bij_W, idx, Sg, pmask, atomF, atomw);
  k_adaln<<<dim3(Bc * Nc / 4), dim3(256), 0, stream>>>(atomw, idx, Tg, Tb, sbuf);
  k_trans1<<<dim3(Bc * Nc / 32, 2), dim3(256), 0, stream>>>(sbuf, t_W1, t_W2, bmid);
  k_trans2<<<dim3(Bc * Nc / 32), dim3(256), 0, stream>>>(bmid, t_Wo, atomw, idx, Tc, pmask,
                                                         (float*)d_out);
}